// Round 3
// baseline (211.192 us; speedup 1.0000x reference)
//
#include <hip/hip_runtime.h>
#include <math.h>

#define F_DIM 64
#define K_CL 16
#define B_GR 16
#define SROW 72   // padded LDS row stride in f16 (144 B) -- used by k_fused only

#define NBKT 4096         // 16 graphs x 256 buckets (16 row-blocks x 16 col-blocks)
#define CAPB 1216         // per-bucket capacity (mean 1024 + 6 sigma)

typedef _Float16 h16;
using f16x4 = __attribute__((ext_vector_type(4))) _Float16;
using f16x8 = __attribute__((ext_vector_type(8))) _Float16;
using f32x4 = __attribute__((ext_vector_type(4))) float;

// ---------------------------------------------------------------------------
// K1 (fused): unchanged from baseline.
// ---------------------------------------------------------------------------
__global__ __launch_bounds__(256) void k_fused(
    const float* __restrict__ x, const float* __restrict__ W, const float* __restrict__ bvec,
    h16* __restrict__ ssh, float* __restrict__ outx, float* __restrict__ CCb)
{
    __shared__ float Wl[F_DIM * K_CL];
    __shared__ float bl[K_CL];
    __shared__ __align__(16) h16 stage[4][(16 + 16 + 64) * SROW];  // 55.3 KB

    int t = threadIdx.x;
    for (int idx = t; idx < F_DIM * K_CL; idx += 256) Wl[idx] = W[idx];
    if (t < K_CL) bl[t] = bvec[t];
    __syncthreads();

    int wid = t >> 6, lane = t & 63;
    h16* Sg = stage[wid];            // sraw^T  [16][SROW]
    h16* Cg = Sg + 16 * SROW;        // ss^T    [16][SROW]
    h16* Xg = Cg + 16 * SROW;        // x^T     [64][SROW]

    size_t i = (size_t)blockIdx.x * 256 + t;
    float s[16];
#pragma unroll
    for (int k = 0; k < 16; ++k) s[k] = bl[k];

    const float4* xp = reinterpret_cast<const float4*>(x + i * F_DIM);
#pragma unroll
    for (int j = 0; j < 16; ++j) {
        float4 q = xp[j];
        float xf[4] = {q.x, q.y, q.z, q.w};
#pragma unroll
        for (int ff = 0; ff < 4; ++ff) {
            int f = j * 4 + ff;
            float xv = xf[ff];
            Xg[f * SROW + lane] = (h16)xv;           // stage x^T
            const float4* wr = reinterpret_cast<const float4*>(&Wl[f * K_CL]);
            float4 w0 = wr[0], w1 = wr[1], w2 = wr[2], w3 = wr[3];
            s[0]  += xv * w0.x; s[1]  += xv * w0.y; s[2]  += xv * w0.z; s[3]  += xv * w0.w;
            s[4]  += xv * w1.x; s[5]  += xv * w1.y; s[6]  += xv * w1.z; s[7]  += xv * w1.w;
            s[8]  += xv * w2.x; s[9]  += xv * w2.y; s[10] += xv * w2.z; s[11] += xv * w2.w;
            s[12] += xv * w3.x; s[13] += xv * w3.y; s[14] += xv * w3.z; s[15] += xv * w3.w;
        }
    }

    // stage sraw^T
#pragma unroll
    for (int k = 0; k < 16; ++k) Sg[k * SROW + lane] = (h16)s[k];

    // softmax
    float m = s[0];
#pragma unroll
    for (int k = 1; k < 16; ++k) m = fmaxf(m, s[k]);
    float sum = 0.f;
#pragma unroll
    for (int k = 0; k < 16; ++k) { s[k] = __expf(s[k] - m); sum += s[k]; }
    float inv = 1.0f / sum;
#pragma unroll
    for (int k = 0; k < 16; ++k) s[k] *= inv;

    // stage ss^T + global ssh write
    f16x8 h0, h1;
#pragma unroll
    for (int k = 0; k < 8; ++k) { h0[k] = (h16)s[k]; h1[k] = (h16)s[k + 8]; }
#pragma unroll
    for (int k = 0; k < 8; ++k) {
        Cg[k * SROW + lane] = h0[k];
        Cg[(k + 8) * SROW + lane] = h1[k];
    }
    f16x8* hp = reinterpret_cast<f16x8*>(ssh + i * K_CL);
    hp[0] = h0;
    hp[1] = h1;

    // MFMA phase (wave-private LDS, no barrier needed)
    int q4 = lane >> 4, mm = lane & 15;
    f32x4 accO[4] = {{0.f,0.f,0.f,0.f},{0.f,0.f,0.f,0.f},{0.f,0.f,0.f,0.f},{0.f,0.f,0.f,0.f}};
    f32x4 accC = {0.f, 0.f, 0.f, 0.f};
#pragma unroll
    for (int h = 0; h < 2; ++h) {
        f16x8 aO = *(const f16x8*)&Sg[mm * SROW + h * 32 + q4 * 8];
        f16x8 aC = *(const f16x8*)&Cg[mm * SROW + h * 32 + q4 * 8];
        accC = __builtin_amdgcn_mfma_f32_16x16x32_f16(aC, aC, accC, 0, 0, 0);
#pragma unroll
        for (int ft = 0; ft < 4; ++ft) {
            f16x8 bO = *(const f16x8*)&Xg[(ft * 16 + mm) * SROW + h * 32 + q4 * 8];
            accO[ft] = __builtin_amdgcn_mfma_f32_16x16x32_f16(aO, bO, accO[ft], 0, 0, 0);
        }
    }
    __syncthreads();

    // block reduce (reuse staging LDS)
    float* redO = (float*)&stage[0][0];     // 4 x 1024
    float* redC = redO + 4096;              // 4 x 256
#pragma unroll
    for (int ft = 0; ft < 4; ++ft)
#pragma unroll
        for (int rg = 0; rg < 4; ++rg)
            redO[wid * 1024 + (q4 * 4 + rg) * 64 + ft * 16 + mm] = accO[ft][rg];
#pragma unroll
    for (int rg = 0; rg < 4; ++rg)
        redC[wid * 256 + (q4 * 4 + rg) * 16 + mm] = accC[rg];
    __syncthreads();

    int g = blockIdx.x >> 5;    // 32 blocks per graph
#pragma unroll
    for (int it = 0; it < 4; ++it) {
        int idx = t + it * 256;
        float v = redO[idx] + redO[1024 + idx] + redO[2048 + idx] + redO[3072 + idx];
        atomicAdd(outx + g * 1024 + idx, v);
    }
    {
        float v = redC[t] + redC[256 + t] + redC[512 + t] + redC[768 + t];
        atomicAdd(CCb + g * 256 + t, v);
    }
}

// ---------------------------------------------------------------------------
// K-bucket (new): partition each graph's edges into 256 buckets of
// (512-node row-block, 512-node col-block). 2048 edges per workgroup
// (128 wg per graph). LDS histogram -> one global atomicAdd per
// (block,bucket) to reserve a contiguous slot range -> scatter packed
// payloads (r9|c9<<16, w f32) = 8 B/edge. galloc ends as per-bucket count.
// ---------------------------------------------------------------------------
__global__ __launch_bounds__(256) void k_bucket(
    const int* __restrict__ erow, const int* __restrict__ ecol, const float* __restrict__ ew,
    unsigned* __restrict__ galloc, uint2* __restrict__ bdata)
{
    __shared__ unsigned hist[256], boff[256], bbase[256];
    int t = threadIdx.x;
    int bid = blockIdx.x;
    int graph = bid >> 7;                     // 128 blocks per graph
    size_t base = (size_t)bid * 2048;
    hist[t] = 0; boff[t] = 0;
    __syncthreads();

    int r[8], c[8], bkt[8]; float w[8];
#pragma unroll
    for (int j = 0; j < 8; ++j) {
        size_t e = base + t + j * 256;
        r[j] = erow[e] & 8191;
        c[j] = ecol[e] & 8191;
        w[j] = ew[e];
        bkt[j] = ((r[j] >> 9) << 4) | (c[j] >> 9);
        atomicAdd(&hist[bkt[j]], 1u);
    }
    __syncthreads();
    {
        unsigned cnt = hist[t];
        bbase[t] = cnt ? atomicAdd(&galloc[graph * 256 + t], cnt) : 0u;
    }
    __syncthreads();
#pragma unroll
    for (int j = 0; j < 8; ++j) {
        unsigned rank = atomicAdd(&boff[bkt[j]], 1u);
        unsigned slot = bbase[bkt[j]] + rank;
        if (slot < CAPB) {                    // 6-sigma guard, ~never taken
            uint2 p;
            p.x = (unsigned)((r[j] & 511) | ((c[j] & 511) << 16));
            p.y = __float_as_uint(w[j]);
            bdata[(size_t)(graph * 256 + bkt[j]) * CAPB + slot] = p;
        }
    }
}

// ---------------------------------------------------------------------------
// K-adj (new): one block per bucket (grid 4096). Stage both 512-row ss
// slices (16 KB each) into LDS once; then per 64-edge tile per wave the
// round-2-verified compute_tile runs with gathers replaced by LDS reads.
// Zero random global line traffic. Tail lanes carry w=0.
// LDS: ssA 16K + ssB 16K + stage 16K + CCl 1K = 49 KB -> 3 blocks/CU.
// ---------------------------------------------------------------------------
__global__ __launch_bounds__(256) void k_adj(
    const h16* __restrict__ ssh, const unsigned* __restrict__ galloc,
    const uint2* __restrict__ bdata, float* __restrict__ oadj)
{
    __shared__ float CCl[256];
    __shared__ __align__(16) h16 ssA[512 * 16];
    __shared__ __align__(16) h16 ssB[512 * 16];
    __shared__ __align__(16) h16 stageE[4][2048];

    int t = threadIdx.x;
    CCl[t] = 0.f;

    int gb = blockIdx.x;
    int graph = gb >> 8, bkt = gb & 255, rb = bkt >> 4, cb = bkt & 15;

    // stage ss caches (coalesced f16x8 copies)
    const f16x8* srcA = (const f16x8*)(ssh + ((size_t)graph * 8192 + (size_t)rb * 512) * 16);
    const f16x8* srcB = (const f16x8*)(ssh + ((size_t)graph * 8192 + (size_t)cb * 512) * 16);
    f16x8* dA = (f16x8*)ssA;
    f16x8* dB = (f16x8*)ssB;
#pragma unroll
    for (int i = 0; i < 4; ++i) {
        dA[t + i * 256] = srcA[t + i * 256];
        dB[t + i * 256] = srcB[t + i * 256];
    }
    unsigned count = galloc[gb];
    __syncthreads();

    int wid = t >> 6, lane = t & 63;
    int q4 = lane >> 4, mm = lane & 15;
    int half = lane & 1, e2l = lane >> 1;     // 2 lanes per edge
    h16* Ag = stageE[wid];
    f16x8* Aw = reinterpret_cast<f16x8*>(Ag);
    using lds_h16 = __attribute__((address_space(3))) h16;
    unsigned trA = (unsigned)(uintptr_t)(lds_h16*)Ag + (unsigned)(q4 * 256 + mm * 2);

    const f16x8* cAf = (const f16x8*)ssA;
    const f16x8* cBf = (const f16x8*)ssB;
    const uint2* bp = bdata + (size_t)gb * CAPB;

    f32x4 acc = {0.f, 0.f, 0.f, 0.f};
    int nt = ((int)count + 255) >> 8;         // tiles of 256 edges block-wide

    for (int it = 0; it < nt; ++it) {
        int e0 = it * 256 + wid * 64 + e2l;   // subtile 0 edge
        int e1 = e0 + 32;                     // subtile 1 edge
        uint2 p0 = make_uint2(0u, 0u), p1 = make_uint2(0u, 0u);
        if (e0 < (int)count) p0 = bp[e0];
        if (e1 < (int)count) p1 = bp[e1];
        float w0 = __uint_as_float(p0.y), w1 = __uint_as_float(p1.y);
        int r0 = p0.x & 511, c0 = (p0.x >> 16) & 511;
        int r1 = p1.x & 511, c1 = (p1.x >> 16) & 511;

        // LDS-cache gathers (random rows within 16 KB; bank-conflicted but cheap)
        f16x8 a0 = cAf[r0 * 2 + half];
        f16x8 a1 = cAf[r1 * 2 + half];
        f16x8 b0 = cBf[c0 * 2 + half];
        f16x8 b1 = cBf[c1 * 2 + half];

        h16 wh0 = (h16)w0, wh1 = (h16)w1;
#pragma unroll
        for (int k = 0; k < 8; ++k) { a0[k] *= wh0; a1[k] *= wh1; }
        Aw[lane]       = a0;   // subtile 0: edges  0..31
        Aw[64  + lane] = a1;   // subtile 1: edges 32..63
        Aw[128 + lane] = b0;
        Aw[192 + lane] = b1;

        f16x4 xa0, xa1, xa2, xa3, xb0, xb1, xb2, xb3;
        asm volatile(
            "ds_read_b64_tr_b16 %0, %8\n\t"
            "ds_read_b64_tr_b16 %1, %8 offset:128\n\t"
            "ds_read_b64_tr_b16 %2, %8 offset:2048\n\t"
            "ds_read_b64_tr_b16 %3, %8 offset:2176\n\t"
            "ds_read_b64_tr_b16 %4, %8 offset:1024\n\t"
            "ds_read_b64_tr_b16 %5, %8 offset:1152\n\t"
            "ds_read_b64_tr_b16 %6, %8 offset:3072\n\t"
            "ds_read_b64_tr_b16 %7, %8 offset:3200\n\t"
            "s_waitcnt lgkmcnt(0)"
            : "=&v"(xa0), "=&v"(xa1), "=&v"(xb0), "=&v"(xb1),
              "=&v"(xa2), "=&v"(xa3), "=&v"(xb2), "=&v"(xb3)
            : "v"(trA)
            : "memory");
        __builtin_amdgcn_sched_barrier(0);

        f16x8 afL = __builtin_shufflevector(xa0, xa1, 0, 1, 2, 3, 4, 5, 6, 7);
        f16x8 bfL = __builtin_shufflevector(xb0, xb1, 0, 1, 2, 3, 4, 5, 6, 7);
        f16x8 afH = __builtin_shufflevector(xa2, xa3, 0, 1, 2, 3, 4, 5, 6, 7);
        f16x8 bfH = __builtin_shufflevector(xb2, xb3, 0, 1, 2, 3, 4, 5, 6, 7);
        acc = __builtin_amdgcn_mfma_f32_16x16x32_f16(afL, bfL, acc, 0, 0, 0);
        acc = __builtin_amdgcn_mfma_f32_16x16x32_f16(afH, bfH, acc, 0, 0, 0);
    }

    // reduce: acc[rg] is oadj[row = q4*4+rg][col = mm] contribution
#pragma unroll
    for (int rg = 0; rg < 4; ++rg)
        atomicAdd(&CCl[(q4 * 4 + rg) * 16 + mm], acc[rg]);
    __syncthreads();
    atomicAdd(oadj + graph * 256 + t, CCl[t]);
}

// ---------------------------------------------------------------------------
// K2 (old, fallback when ws too small): round-2 pair-split gather version.
// ---------------------------------------------------------------------------
__global__ __launch_bounds__(256) void k_edge(
    const int* __restrict__ erow, const int* __restrict__ ecol, const float* __restrict__ ew,
    const h16* __restrict__ ssh, float* __restrict__ oadj,
    int edges_per_block, int edges_per_graph, int nmask)
{
    __shared__ float CCl[256];
    __shared__ __align__(16) h16 stageE[4][2048];
    int t = threadIdx.x;
    CCl[t] = 0.f;
    __syncthreads();

    int bid = blockIdx.x;
    int xcd = bid & 7;
    int slot = bid >> 3;
    int graph = xcd + 8 * (slot & 1);
    int chunk = slot >> 1;

    int wid = t >> 6, lane = t & 63;
    int q4 = lane >> 4, mm = lane & 15;
    int half = lane & 1, e2l = lane >> 1;
    h16* Ag = stageE[wid];

    int epw = edges_per_block >> 2;
    int nt  = epw >> 6;
    size_t base = (size_t)graph * edges_per_graph
                + (size_t)chunk * edges_per_block
                + (size_t)wid * epw
                + e2l;

    const f16x8* sshp = reinterpret_cast<const f16x8*>(ssh);
    f32x4 acc = {0.f, 0.f, 0.f, 0.f};

    f16x8* Aw = reinterpret_cast<f16x8*>(Ag);
    using lds_h16 = __attribute__((address_space(3))) h16;
    unsigned trA = (unsigned)(uintptr_t)(lds_h16*)Ag + (unsigned)(q4 * 256 + mm * 2);

    auto compute_tile = [&](f16x8 a0, f16x8 a1, f16x8 b0, f16x8 b1,
                            float w0v, float w1v) {
        h16 wh0 = (h16)w0v, wh1 = (h16)w1v;
#pragma unroll
        for (int k = 0; k < 8; ++k) { a0[k] *= wh0; a1[k] *= wh1; }
        Aw[lane]        = a0;
        Aw[64  + lane]  = a1;
        Aw[128 + lane]  = b0;
        Aw[192 + lane]  = b1;

        f16x4 xa0, xa1, xa2, xa3, xb0, xb1, xb2, xb3;
        asm volatile(
            "ds_read_b64_tr_b16 %0, %8\n\t"
            "ds_read_b64_tr_b16 %1, %8 offset:128\n\t"
            "ds_read_b64_tr_b16 %2, %8 offset:2048\n\t"
            "ds_read_b64_tr_b16 %3, %8 offset:2176\n\t"
            "ds_read_b64_tr_b16 %4, %8 offset:1024\n\t"
            "ds_read_b64_tr_b16 %5, %8 offset:1152\n\t"
            "ds_read_b64_tr_b16 %6, %8 offset:3072\n\t"
            "ds_read_b64_tr_b16 %7, %8 offset:3200\n\t"
            "s_waitcnt lgkmcnt(0)"
            : "=&v"(xa0), "=&v"(xa1), "=&v"(xb0), "=&v"(xb1),
              "=&v"(xa2), "=&v"(xa3), "=&v"(xb2), "=&v"(xb3)
            : "v"(trA)
            : "memory");
        __builtin_amdgcn_sched_barrier(0);

        f16x8 afL = __builtin_shufflevector(xa0, xa1, 0, 1, 2, 3, 4, 5, 6, 7);
        f16x8 bfL = __builtin_shufflevector(xb0, xb1, 0, 1, 2, 3, 4, 5, 6, 7);
        f16x8 afH = __builtin_shufflevector(xa2, xa3, 0, 1, 2, 3, 4, 5, 6, 7);
        f16x8 bfH = __builtin_shufflevector(xb2, xb3, 0, 1, 2, 3, 4, 5, 6, 7);
        acc = __builtin_amdgcn_mfma_f32_16x16x32_f16(afL, bfL, acc, 0, 0, 0);
        acc = __builtin_amdgcn_mfma_f32_16x16x32_f16(afH, bfH, acc, 0, 0, 0);
    };

    int r0C, c0C, r1C, c1C; float w0C, w1C;
    r0C = erow[base];      c0C = ecol[base];      w0C = ew[base];
    r1C = erow[base + 32]; c1C = ecol[base + 32]; w1C = ew[base + 32];
    f16x8 ca0 = sshp[2 * (size_t)(r0C & nmask) + half];
    f16x8 ca1 = sshp[2 * (size_t)(r1C & nmask) + half];
    f16x8 cb0 = sshp[2 * (size_t)(c0C & nmask) + half];
    f16x8 cb1 = sshp[2 * (size_t)(c1C & nmask) + half];
    int r0N = 0, c0N = 0, r1N = 0, c1N = 0; float w0N = 0.f, w1N = 0.f;
    if (nt > 1) {
        size_t e = base + 64;
        r0N = erow[e];      c0N = ecol[e];      w0N = ew[e];
        r1N = erow[e + 32]; c1N = ecol[e + 32]; w1N = ew[e + 32];
    }

    for (int tt = 0; tt < nt - 1; ++tt) {
        f16x8 na0 = sshp[2 * (size_t)(r0N & nmask) + half];
        f16x8 na1 = sshp[2 * (size_t)(r1N & nmask) + half];
        f16x8 nb0 = sshp[2 * (size_t)(c0N & nmask) + half];
        f16x8 nb1 = sshp[2 * (size_t)(c1N & nmask) + half];
        int t2 = (tt + 2 < nt) ? (tt + 2) : 0;
        size_t e2 = base + (size_t)t2 * 64;
        int r02 = erow[e2],      c02 = ecol[e2];      float w02 = ew[e2];
        int r12 = erow[e2 + 32], c12 = ecol[e2 + 32]; float w12 = ew[e2 + 32];

        compute_tile(ca0, ca1, cb0, cb1, w0C, w1C);

        ca0 = na0; ca1 = na1; cb0 = nb0; cb1 = nb1;
        w0C = w0N; w1C = w1N;
        r0N = r02; c0N = c02; w0N = w02;
        r1N = r12; c1N = c12; w1N = w12;
    }
    compute_tile(ca0, ca1, cb0, cb1, w0C, w1C);

#pragma unroll
    for (int rg = 0; rg < 4; ++rg)
        atomicAdd(&CCl[(q4 * 4 + rg) * 16 + mm], acc[rg]);
    __syncthreads();
    atomicAdd(oadj + graph * 256 + t, CCl[t]);
}

// ---------------------------------------------------------------------------
// K3: unchanged from baseline.
// ---------------------------------------------------------------------------
__global__ __launch_bounds__(256) void k_final(
    const float* __restrict__ outx, const float* __restrict__ oadj,
    const float* __restrict__ CCb, float* __restrict__ out, int npg)
{
    int t = threadIdx.x;
    int gid = blockIdx.x * 256 + t;
    {
        float v = outx[gid];
        float r = (v > 0.f) ? (1.0507009873554805f * v)
                            : (1.0507009873554805f * 1.6732632423543772f * (__expf(v) - 1.0f));
        out[gid] = r;
    }

    if (blockIdx.x != 0) return;

    int b = t >> 4, k = t & 15;
    const float* oar = oadj + b * 256 + k * 16;
    const float* ccr = CCb + b * 256 + k * 16;

    float rowsum_off = 0.f, trace_c = 0.f, rowsum_all = 0.f, fro2 = 0.f, colsum = 0.f;
    float csv = 0.f;
#pragma unroll
    for (int l = 0; l < 16; ++l) {
        float v = oar[l];
        rowsum_all += v;
        if (l == k) trace_c = v; else rowsum_off += v;
        float c = ccr[l];
        fro2 += c * c;
        csv += c;
        colsum += oadj[b * 256 + l * 16 + k];
    }
    float dd = sqrtf(rowsum_off) + 1e-12f;
    __shared__ float ddl[B_GR * K_CL];
    ddl[t] = dd;

    float ds2 = colsum * colsum, cs2 = csv * csv;
    float tr = trace_c, m2 = rowsum_all;
#pragma unroll
    for (int msk = 8; msk >= 1; msk >>= 1) {
        tr   += __shfl_xor(tr,   msk, 16);
        ds2  += __shfl_xor(ds2,  msk, 16);
        cs2  += __shfl_xor(cs2,  msk, 16);
        fro2 += __shfl_xor(fro2, msk, 16);
        m2   += __shfl_xor(m2,   msk, 16);
    }
    float invfro = 1.0f / sqrtf(fro2);
    float osum = 0.f;
#pragma unroll
    for (int l = 0; l < 16; ++l) {
        float v = ccr[l] * invfro - ((l == k) ? 0.25f : 0.f);
        osum += v * v;
    }
#pragma unroll
    for (int msk = 8; msk >= 1; msk >>= 1) osum += __shfl_xor(osum, msk, 16);

    __shared__ float sp_s[B_GR], cl_s[B_GR], or_s[B_GR];
    if (k == 0) {
        sp_s[b] = tr / m2 - ds2 / (m2 * m2);
        cl_s[b] = sqrtf(cs2) / (float)npg * 4.0f - 1.0f;
        or_s[b] = sqrtf(osum);
    }
    __syncthreads();
    if (t == 0) {
        float a = 0.f, c = 0.f, o = 0.f;
        for (int i = 0; i < B_GR; ++i) { a += sp_s[i]; c += cl_s[i]; o += or_s[i]; }
        out[20480] = -a / 16.f;
        out[20481] = c / 16.f;
        out[20482] = o / 16.f;
    }

#pragma unroll
    for (int l = 0; l < 16; ++l) {
        float v = (l == k) ? 0.f : oar[l] / (dd * ddl[b * 16 + l]);
        out[16384 + b * 256 + k * 16 + l] = v;
    }
}

// ---------------------------------------------------------------------------
extern "C" void kernel_launch(void* const* d_in, const int* in_sizes, int n_in,
                              void* d_out, int out_size, void* d_ws, size_t ws_size,
                              hipStream_t stream)
{
    const float* x    = (const float*)d_in[0];
    const float* W    = (const float*)d_in[1];
    const float* bvec = (const float*)d_in[2];
    const float* ew   = (const float*)d_in[3];
    const int* erow   = (const int*)d_in[4];
    const int* ecol   = (const int*)d_in[5];

    int Ntot = in_sizes[0] / F_DIM;           // 131072
    size_t E = (size_t)in_sizes[3];           // 4194304
    int npg  = Ntot / B_GR;                   // 8192
    int edges_per_graph = (int)(E / B_GR);    // 262144
    int nmask = Ntot - 1;

    char* ws = (char*)d_ws;
    size_t o = 0;
    h16*   ssh   = (h16*)(ws + o);   o += (size_t)Ntot * 16 * 2;
    size_t zoff = o;
    float* outx  = (float*)(ws + o); o += (size_t)B_GR * 1024 * 4;
    float* oadj  = (float*)(ws + o); o += (size_t)B_GR * 256 * 4;
    float* CCb   = (float*)(ws + o); o += (size_t)B_GR * 256 * 4;
    unsigned* galloc = (unsigned*)(ws + o); o += (size_t)NBKT * 4;
    size_t zend = o;
    uint2* bdata = (uint2*)(ws + o); o += (size_t)NBKT * CAPB * 8;

    bool use_bucket = (ws_size >= o);

    hipMemsetAsync(ws + zoff, 0, zend - zoff, stream);

    k_fused<<<Ntot / 256, 256, 0, stream>>>(x, W, bvec, ssh, outx, CCb);

    if (use_bucket) {
        k_bucket<<<2048, 256, 0, stream>>>(erow, ecol, ew, galloc, bdata);
        k_adj<<<NBKT, 256, 0, stream>>>(ssh, galloc, bdata, oadj);
    } else {
        const int ADJ_BLOCKS = 2048;
        int edges_per_block = (int)(E / ADJ_BLOCKS);
        k_edge<<<ADJ_BLOCKS, 256, 0, stream>>>(erow, ecol, ew, ssh, oadj,
                                               edges_per_block, edges_per_graph, nmask);
    }

    k_final<<<64, 256, 0, stream>>>(outx, oadj, CCb, (float*)d_out, npg);
}

// Round 4
// 178.092 us; speedup vs baseline: 1.1859x; 1.1859x over previous
//
#include <hip/hip_runtime.h>
#include <math.h>

#define F_DIM 64
#define K_CL 16
#define B_GR 16
#define SROW 72   // padded LDS row stride in f16 (144 B) -- used by k_fused only

typedef _Float16 h16;
using f16x4 = __attribute__((ext_vector_type(4))) _Float16;
using f16x8 = __attribute__((ext_vector_type(8))) _Float16;
using f32x4 = __attribute__((ext_vector_type(4))) float;

// ---------------------------------------------------------------------------
// K1 (fused): unchanged from baseline.
// ---------------------------------------------------------------------------
__global__ __launch_bounds__(256) void k_fused(
    const float* __restrict__ x, const float* __restrict__ W, const float* __restrict__ bvec,
    h16* __restrict__ ssh, float* __restrict__ outx, float* __restrict__ CCb)
{
    __shared__ float Wl[F_DIM * K_CL];
    __shared__ float bl[K_CL];
    __shared__ __align__(16) h16 stage[4][(16 + 16 + 64) * SROW];  // 55.3 KB

    int t = threadIdx.x;
    for (int idx = t; idx < F_DIM * K_CL; idx += 256) Wl[idx] = W[idx];
    if (t < K_CL) bl[t] = bvec[t];
    __syncthreads();

    int wid = t >> 6, lane = t & 63;
    h16* Sg = stage[wid];            // sraw^T  [16][SROW]
    h16* Cg = Sg + 16 * SROW;        // ss^T    [16][SROW]
    h16* Xg = Cg + 16 * SROW;        // x^T     [64][SROW]

    size_t i = (size_t)blockIdx.x * 256 + t;
    float s[16];
#pragma unroll
    for (int k = 0; k < 16; ++k) s[k] = bl[k];

    const float4* xp = reinterpret_cast<const float4*>(x + i * F_DIM);
#pragma unroll
    for (int j = 0; j < 16; ++j) {
        float4 q = xp[j];
        float xf[4] = {q.x, q.y, q.z, q.w};
#pragma unroll
        for (int ff = 0; ff < 4; ++ff) {
            int f = j * 4 + ff;
            float xv = xf[ff];
            Xg[f * SROW + lane] = (h16)xv;           // stage x^T
            const float4* wr = reinterpret_cast<const float4*>(&Wl[f * K_CL]);
            float4 w0 = wr[0], w1 = wr[1], w2 = wr[2], w3 = wr[3];
            s[0]  += xv * w0.x; s[1]  += xv * w0.y; s[2]  += xv * w0.z; s[3]  += xv * w0.w;
            s[4]  += xv * w1.x; s[5]  += xv * w1.y; s[6]  += xv * w1.z; s[7]  += xv * w1.w;
            s[8]  += xv * w2.x; s[9]  += xv * w2.y; s[10] += xv * w2.z; s[11] += xv * w2.w;
            s[12] += xv * w3.x; s[13] += xv * w3.y; s[14] += xv * w3.z; s[15] += xv * w3.w;
        }
    }

    // stage sraw^T
#pragma unroll
    for (int k = 0; k < 16; ++k) Sg[k * SROW + lane] = (h16)s[k];

    // softmax
    float m = s[0];
#pragma unroll
    for (int k = 1; k < 16; ++k) m = fmaxf(m, s[k]);
    float sum = 0.f;
#pragma unroll
    for (int k = 0; k < 16; ++k) { s[k] = __expf(s[k] - m); sum += s[k]; }
    float inv = 1.0f / sum;
#pragma unroll
    for (int k = 0; k < 16; ++k) s[k] *= inv;

    // stage ss^T + global ssh write
    f16x8 h0, h1;
#pragma unroll
    for (int k = 0; k < 8; ++k) { h0[k] = (h16)s[k]; h1[k] = (h16)s[k + 8]; }
#pragma unroll
    for (int k = 0; k < 8; ++k) {
        Cg[k * SROW + lane] = h0[k];
        Cg[(k + 8) * SROW + lane] = h1[k];
    }
    f16x8* hp = reinterpret_cast<f16x8*>(ssh + i * K_CL);
    hp[0] = h0;
    hp[1] = h1;

    // MFMA phase (wave-private LDS, no barrier needed)
    int q4 = lane >> 4, mm = lane & 15;
    f32x4 accO[4] = {{0.f,0.f,0.f,0.f},{0.f,0.f,0.f,0.f},{0.f,0.f,0.f,0.f},{0.f,0.f,0.f,0.f}};
    f32x4 accC = {0.f, 0.f, 0.f, 0.f};
#pragma unroll
    for (int h = 0; h < 2; ++h) {
        f16x8 aO = *(const f16x8*)&Sg[mm * SROW + h * 32 + q4 * 8];
        f16x8 aC = *(const f16x8*)&Cg[mm * SROW + h * 32 + q4 * 8];
        accC = __builtin_amdgcn_mfma_f32_16x16x32_f16(aC, aC, accC, 0, 0, 0);
#pragma unroll
        for (int ft = 0; ft < 4; ++ft) {
            f16x8 bO = *(const f16x8*)&Xg[(ft * 16 + mm) * SROW + h * 32 + q4 * 8];
            accO[ft] = __builtin_amdgcn_mfma_f32_16x16x32_f16(aO, bO, accO[ft], 0, 0, 0);
        }
    }
    __syncthreads();

    // block reduce (reuse staging LDS)
    float* redO = (float*)&stage[0][0];     // 4 x 1024
    float* redC = redO + 4096;              // 4 x 256
#pragma unroll
    for (int ft = 0; ft < 4; ++ft)
#pragma unroll
        for (int rg = 0; rg < 4; ++rg)
            redO[wid * 1024 + (q4 * 4 + rg) * 64 + ft * 16 + mm] = accO[ft][rg];
#pragma unroll
    for (int rg = 0; rg < 4; ++rg)
        redC[wid * 256 + (q4 * 4 + rg) * 16 + mm] = accC[rg];
    __syncthreads();

    int g = blockIdx.x >> 5;    // 32 blocks per graph
#pragma unroll
    for (int it = 0; it < 4; ++it) {
        int idx = t + it * 256;
        float v = redO[idx] + redO[1024 + idx] + redO[2048 + idx] + redO[3072 + idx];
        atomicAdd(outx + g * 1024 + idx, v);
    }
    {
        float v = redC[t] + redC[256 + t] + redC[512 + t] + redC[768 + t];
        atomicAdd(CCb + g * 256 + t, v);
    }
}

// ---------------------------------------------------------------------------
// K2 v5: oadj via MFMA, LDS round-trip software-pipelined IN THE SAME BUFFER
// using DS in-order completion:
//   iter tt: [8 tr-reads of tile tt-1 data]  (no wait)
//            [scale + 4 ds_write_b128 of tile tt]  (queue behind reads)
//            [issue gathers tt+1, idx loads tt+2]  (vmcnt, in flight)
//            [s_waitcnt lgkmcnt(4)] -> tr data ready, writes still draining
//            [sched_barrier(0); 2 MFMAs on tile tt-1]
// Exposed stall per tile drops from write+read LDS latency (~300-400 cy)
// to ~max(0, tr latency - issue work). Stores/waits are inline asm so the
// counted lgkmcnt(4) is exact. Gather scheme = round-2 pair-split (2 lanes
// per edge, 16B half-rows, cache-line coalesced within the instruction).
// ---------------------------------------------------------------------------
__global__ __launch_bounds__(256) void k_edge(
    const int* __restrict__ erow, const int* __restrict__ ecol, const float* __restrict__ ew,
    const h16* __restrict__ ssh, float* __restrict__ oadj,
    int edges_per_block, int edges_per_graph, int nmask)
{
    __shared__ float CCl[256];
    __shared__ __align__(16) h16 stageE[4][2048];   // per wave: A[64][16] + B[64][16] = 4 KB
    int t = threadIdx.x;
    CCl[t] = 0.f;
    __syncthreads();

    int bid = blockIdx.x;
    int xcd = bid & 7;
    int slot = bid >> 3;
    int graph = xcd + 8 * (slot & 1);
    int chunk = slot >> 1;

    int wid = t >> 6, lane = t & 63;
    int q4 = lane >> 4, mm = lane & 15;
    int half = lane & 1, e2l = lane >> 1;   // 2 lanes per edge
    h16* Ag = stageE[wid];

    int epw = edges_per_block >> 2;           // 512 edges per wave
    int nt  = epw >> 6;                       // 8 tiles of 64 edges
    size_t base = (size_t)graph * edges_per_graph
                + (size_t)chunk * edges_per_block
                + (size_t)wid * epw
                + e2l;                        // this lane's edge slot (subtile 0)

    const f16x8* sshp = reinterpret_cast<const f16x8*>(ssh);
    f32x4 acc = {0.f, 0.f, 0.f, 0.f};

    using lds_h16 = __attribute__((address_space(3))) h16;
    unsigned wbase = (unsigned)(uintptr_t)(lds_h16*)Ag;
    unsigned st_addr = wbase + (unsigned)(lane * 16);          // per-lane store slot
    unsigned trA     = wbase + (unsigned)(q4 * 256 + mm * 2);  // tr-read base

    // fragment registers produced by the tr-read phase (consumed same iter)
    f16x4 xa0, xa1, xa2, xa3, xb0, xb1, xb2, xb3;

    // (a) issue 8 transpose reads of the PREVIOUS tile's staged data
    auto issue_tr = [&]() {
        asm volatile(
            "ds_read_b64_tr_b16 %0, %8\n\t"
            "ds_read_b64_tr_b16 %1, %8 offset:128\n\t"
            "ds_read_b64_tr_b16 %2, %8 offset:2048\n\t"
            "ds_read_b64_tr_b16 %3, %8 offset:2176\n\t"
            "ds_read_b64_tr_b16 %4, %8 offset:1024\n\t"
            "ds_read_b64_tr_b16 %5, %8 offset:1152\n\t"
            "ds_read_b64_tr_b16 %6, %8 offset:3072\n\t"
            "ds_read_b64_tr_b16 %7, %8 offset:3200"
            : "=&v"(xa0), "=&v"(xa1), "=&v"(xb0), "=&v"(xb1),
              "=&v"(xa2), "=&v"(xa3), "=&v"(xb2), "=&v"(xb3)
            : "v"(trA)
            : "memory");
    };

    // (b) scale current tile's A rows by w and stage all 4 fragments
    auto stage_tile = [&](f16x8 a0, f16x8 a1, f16x8 b0, f16x8 b1,
                          float w0v, float w1v) {
        h16 wh0 = (h16)w0v, wh1 = (h16)w1v;
#pragma unroll
        for (int k = 0; k < 8; ++k) { a0[k] *= wh0; a1[k] *= wh1; }
        asm volatile(
            "ds_write_b128 %0, %1\n\t"
            "ds_write_b128 %0, %2 offset:1024\n\t"
            "ds_write_b128 %0, %3 offset:2048\n\t"
            "ds_write_b128 %0, %4 offset:3072"
            :
            : "v"(st_addr), "v"(a0), "v"(a1), "v"(b0), "v"(b1)
            : "memory");
    };

    // (d) wait for tr-reads only (4 writes still outstanding), then MFMA
    auto mfma_prev = [&]() {
        asm volatile("s_waitcnt lgkmcnt(4)" ::: "memory");
        __builtin_amdgcn_sched_barrier(0);
        f16x8 afL = __builtin_shufflevector(xa0, xa1, 0, 1, 2, 3, 4, 5, 6, 7);
        f16x8 bfL = __builtin_shufflevector(xb0, xb1, 0, 1, 2, 3, 4, 5, 6, 7);
        f16x8 afH = __builtin_shufflevector(xa2, xa3, 0, 1, 2, 3, 4, 5, 6, 7);
        f16x8 bfH = __builtin_shufflevector(xb2, xb3, 0, 1, 2, 3, 4, 5, 6, 7);
        acc = __builtin_amdgcn_mfma_f32_16x16x32_f16(afL, bfL, acc, 0, 0, 0);
        acc = __builtin_amdgcn_mfma_f32_16x16x32_f16(afH, bfH, acc, 0, 0, 0);
    };

    // ---- pipeline prologue: idx(0), gathers(0), idx(1) ----
    int r0C, c0C, r1C, c1C; float w0C, w1C;
    r0C = erow[base];      c0C = ecol[base];      w0C = ew[base];
    r1C = erow[base + 32]; c1C = ecol[base + 32]; w1C = ew[base + 32];
    f16x8 ca0 = sshp[2 * (size_t)(r0C & nmask) + half];
    f16x8 ca1 = sshp[2 * (size_t)(r1C & nmask) + half];
    f16x8 cb0 = sshp[2 * (size_t)(c0C & nmask) + half];
    f16x8 cb1 = sshp[2 * (size_t)(c1C & nmask) + half];
    int r0N = 0, c0N = 0, r1N = 0, c1N = 0; float w0N = 0.f, w1N = 0.f;
    {
        size_t e = base + 64;
        r0N = erow[e];      c0N = ecol[e];      w0N = ew[e];
        r1N = erow[e + 32]; c1N = ecol[e + 32]; w1N = ew[e + 32];
    }

    // ---- iteration 0 (peeled: no tr/MFMA yet) ----
    stage_tile(ca0, ca1, cb0, cb1, w0C, w1C);
    {
        f16x8 na0 = sshp[2 * (size_t)(r0N & nmask) + half];
        f16x8 na1 = sshp[2 * (size_t)(r1N & nmask) + half];
        f16x8 nb0 = sshp[2 * (size_t)(c0N & nmask) + half];
        f16x8 nb1 = sshp[2 * (size_t)(c1N & nmask) + half];
        size_t e2 = base + 128;               // idx(2); nt == 8 always here
        r0C = erow[e2];      c0C = ecol[e2];      w0C = ew[e2];
        r1C = erow[e2 + 32]; c1C = ecol[e2 + 32]; w1C = ew[e2 + 32];
        // rotate: cur <- gathered(1); N-idx <- idx(2)
        ca0 = na0; ca1 = na1; cb0 = nb0; cb1 = nb1;
        float tw0 = w0N, tw1 = w1N;
        w0N = w0C; w1N = w1C; r0N = r0C; c0N = c0C; r1N = r1C; c1N = c1C;
        w0C = tw0; w1C = tw1;
    }

    // ---- steady state: tt = 1 .. nt-1 ----
    for (int tt = 1; tt < nt; ++tt) {
        issue_tr();                                   // reads tile tt-1 (in-order DS)
        stage_tile(ca0, ca1, cb0, cb1, w0C, w1C);     // overwrites with tile tt
        // gathers for tile tt+1 (clamped on last iter; redundant but harmless)
        f16x8 na0 = sshp[2 * (size_t)(r0N & nmask) + half];
        f16x8 na1 = sshp[2 * (size_t)(r1N & nmask) + half];
        f16x8 nb0 = sshp[2 * (size_t)(c0N & nmask) + half];
        f16x8 nb1 = sshp[2 * (size_t)(c1N & nmask) + half];
        // idx loads for tile tt+2 (clamped)
        int t2 = (tt + 2 < nt) ? (tt + 2) : 0;
        size_t e2 = base + (size_t)t2 * 64;
        int r02 = erow[e2],      c02 = ecol[e2];      float w02 = ew[e2];
        int r12 = erow[e2 + 32], c12 = ecol[e2 + 32]; float w12 = ew[e2 + 32];

        mfma_prev();                                  // lgkmcnt(4) + MFMA(tt-1)

        ca0 = na0; ca1 = na1; cb0 = nb0; cb1 = nb1;
        w0C = w0N; w1C = w1N;
        r0N = r02; c0N = c02; w0N = w02;
        r1N = r12; c1N = c12; w1N = w12;
    }

    // ---- epilogue: last staged tile ----
    issue_tr();
    asm volatile("s_waitcnt lgkmcnt(0)" ::: "memory");
    __builtin_amdgcn_sched_barrier(0);
    {
        f16x8 afL = __builtin_shufflevector(xa0, xa1, 0, 1, 2, 3, 4, 5, 6, 7);
        f16x8 bfL = __builtin_shufflevector(xb0, xb1, 0, 1, 2, 3, 4, 5, 6, 7);
        f16x8 afH = __builtin_shufflevector(xa2, xa3, 0, 1, 2, 3, 4, 5, 6, 7);
        f16x8 bfH = __builtin_shufflevector(xb2, xb3, 0, 1, 2, 3, 4, 5, 6, 7);
        acc = __builtin_amdgcn_mfma_f32_16x16x32_f16(afL, bfL, acc, 0, 0, 0);
        acc = __builtin_amdgcn_mfma_f32_16x16x32_f16(afH, bfH, acc, 0, 0, 0);
    }

    // reduce: acc[rg] is oadj[row = q4*4+rg][col = mm] contribution
#pragma unroll
    for (int rg = 0; rg < 4; ++rg)
        atomicAdd(&CCl[(q4 * 4 + rg) * 16 + mm], acc[rg]);
    __syncthreads();
    atomicAdd(oadj + graph * 256 + t, CCl[t]);
}

// ---------------------------------------------------------------------------
// K3: unchanged from baseline.
// ---------------------------------------------------------------------------
__global__ __launch_bounds__(256) void k_final(
    const float* __restrict__ outx, const float* __restrict__ oadj,
    const float* __restrict__ CCb, float* __restrict__ out, int npg)
{
    int t = threadIdx.x;
    int gid = blockIdx.x * 256 + t;
    {
        float v = outx[gid];
        float r = (v > 0.f) ? (1.0507009873554805f * v)
                            : (1.0507009873554805f * 1.6732632423543772f * (__expf(v) - 1.0f));
        out[gid] = r;
    }

    if (blockIdx.x != 0) return;

    int b = t >> 4, k = t & 15;
    const float* oar = oadj + b * 256 + k * 16;
    const float* ccr = CCb + b * 256 + k * 16;

    float rowsum_off = 0.f, trace_c = 0.f, rowsum_all = 0.f, fro2 = 0.f, colsum = 0.f;
    float csv = 0.f;
#pragma unroll
    for (int l = 0; l < 16; ++l) {
        float v = oar[l];
        rowsum_all += v;
        if (l == k) trace_c = v; else rowsum_off += v;
        float c = ccr[l];
        fro2 += c * c;
        csv += c;                              // cluster_size[k] = sum_l CC[k][l]
        colsum += oadj[b * 256 + l * 16 + k];
    }
    float dd = sqrtf(rowsum_off) + 1e-12f;
    __shared__ float ddl[B_GR * K_CL];
    ddl[t] = dd;

    float ds2 = colsum * colsum, cs2 = csv * csv;
    float tr = trace_c, m2 = rowsum_all;
#pragma unroll
    for (int msk = 8; msk >= 1; msk >>= 1) {
        tr   += __shfl_xor(tr,   msk, 16);
        ds2  += __shfl_xor(ds2,  msk, 16);
        cs2  += __shfl_xor(cs2,  msk, 16);
        fro2 += __shfl_xor(fro2, msk, 16);
        m2   += __shfl_xor(m2,   msk, 16);
    }
    float invfro = 1.0f / sqrtf(fro2);
    float osum = 0.f;
#pragma unroll
    for (int l = 0; l < 16; ++l) {
        float v = ccr[l] * invfro - ((l == k) ? 0.25f : 0.f);
        osum += v * v;
    }
#pragma unroll
    for (int msk = 8; msk >= 1; msk >>= 1) osum += __shfl_xor(osum, msk, 16);

    __shared__ float sp_s[B_GR], cl_s[B_GR], or_s[B_GR];
    if (k == 0) {
        sp_s[b] = tr / m2 - ds2 / (m2 * m2);
        cl_s[b] = sqrtf(cs2) / (float)npg * 4.0f - 1.0f;
        or_s[b] = sqrtf(osum);
    }
    __syncthreads();
    if (t == 0) {
        float a = 0.f, c = 0.f, o = 0.f;
        for (int i = 0; i < B_GR; ++i) { a += sp_s[i]; c += cl_s[i]; o += or_s[i]; }
        out[20480] = -a / 16.f;
        out[20481] = c / 16.f;
        out[20482] = o / 16.f;
    }

#pragma unroll
    for (int l = 0; l < 16; ++l) {
        float v = (l == k) ? 0.f : oar[l] / (dd * ddl[b * 16 + l]);
        out[16384 + b * 256 + k * 16 + l] = v;
    }
}

// ---------------------------------------------------------------------------
extern "C" void kernel_launch(void* const* d_in, const int* in_sizes, int n_in,
                              void* d_out, int out_size, void* d_ws, size_t ws_size,
                              hipStream_t stream)
{
    const float* x    = (const float*)d_in[0];
    const float* W    = (const float*)d_in[1];
    const float* bvec = (const float*)d_in[2];
    const float* ew   = (const float*)d_in[3];
    const int* erow   = (const int*)d_in[4];
    const int* ecol   = (const int*)d_in[5];

    int Ntot = in_sizes[0] / F_DIM;           // 131072
    size_t E = (size_t)in_sizes[3];           // 4194304
    int npg  = Ntot / B_GR;                   // 8192
    int edges_per_graph = (int)(E / B_GR);    // 262144
    int nmask = Ntot - 1;

    const int ADJ_BLOCKS = 2048;              // 128 per graph, 8 per CU
    int edges_per_block = (int)(E / ADJ_BLOCKS);          // 2048

    char* ws = (char*)d_ws;
    size_t o = 0;
    h16*   ssh   = (h16*)(ws + o);   o += (size_t)Ntot * 16 * 2;
    size_t zoff = o;
    float* outx  = (float*)(ws + o); o += (size_t)B_GR * 1024 * 4;
    float* oadj  = (float*)(ws + o); o += (size_t)B_GR * 256 * 4;
    float* CCb   = (float*)(ws + o); o += (size_t)B_GR * 256 * 4;

    hipMemsetAsync(ws + zoff, 0, o - zoff, stream);

    k_fused<<<Ntot / 256, 256, 0, stream>>>(x, W, bvec, ssh, outx, CCb);
    k_edge<<<ADJ_BLOCKS, 256, 0, stream>>>(erow, ecol, ew, ssh, oadj,
                                           edges_per_block, edges_per_graph, nmask);
    k_final<<<64, 256, 0, stream>>>(outx, oadj, CCb, (float*)d_out, npg);
}

// Round 6
// 173.119 us; speedup vs baseline: 1.2199x; 1.0287x over previous
//
#include <hip/hip_runtime.h>
#include <math.h>

#define F_DIM 64
#define K_CL 16
#define B_GR 16
#define SROW 72   // padded LDS row stride in f16 (144 B) -- used by k_fused only

typedef _Float16 h16;
using f16x4 = __attribute__((ext_vector_type(4))) _Float16;
using f16x8 = __attribute__((ext_vector_type(8))) _Float16;
using f32x4 = __attribute__((ext_vector_type(4))) float;
using fx2   = __attribute__((ext_vector_type(2))) float;
using fp16x2 = __attribute__((ext_vector_type(2))) __fp16;   // cvt_pkrtz return type

static __device__ inline unsigned h2u(fp16x2 h) {
    union { fp16x2 h; unsigned u; } x; x.h = h; return x.u;
}

// ---------------------------------------------------------------------------
// K1 (fused): identical compute; ssh now stored as fp8 e4m3 (16 B/node,
// packed via v_cvt_pk_fp8_f32) -- halves ssh write traffic and, crucially,
// halves k_edge's divergent gather ADDRESS count. CC/outx still f16/f32.
// ---------------------------------------------------------------------------
__global__ __launch_bounds__(256) void k_fused(
    const float* __restrict__ x, const float* __restrict__ W, const float* __restrict__ bvec,
    uint4* __restrict__ ssh8, float* __restrict__ outx, float* __restrict__ CCb)
{
    __shared__ float Wl[F_DIM * K_CL];
    __shared__ float bl[K_CL];
    __shared__ __align__(16) h16 stage[4][(16 + 16 + 64) * SROW];  // 55.3 KB

    int t = threadIdx.x;
    for (int idx = t; idx < F_DIM * K_CL; idx += 256) Wl[idx] = W[idx];
    if (t < K_CL) bl[t] = bvec[t];
    __syncthreads();

    int wid = t >> 6, lane = t & 63;
    h16* Sg = stage[wid];            // sraw^T  [16][SROW]
    h16* Cg = Sg + 16 * SROW;        // ss^T    [16][SROW]
    h16* Xg = Cg + 16 * SROW;        // x^T     [64][SROW]

    size_t i = (size_t)blockIdx.x * 256 + t;
    float s[16];
#pragma unroll
    for (int k = 0; k < 16; ++k) s[k] = bl[k];

    const float4* xp = reinterpret_cast<const float4*>(x + i * F_DIM);
#pragma unroll
    for (int j = 0; j < 16; ++j) {
        float4 q = xp[j];
        float xf[4] = {q.x, q.y, q.z, q.w};
#pragma unroll
        for (int ff = 0; ff < 4; ++ff) {
            int f = j * 4 + ff;
            float xv = xf[ff];
            Xg[f * SROW + lane] = (h16)xv;           // stage x^T
            const float4* wr = reinterpret_cast<const float4*>(&Wl[f * K_CL]);
            float4 w0 = wr[0], w1 = wr[1], w2 = wr[2], w3 = wr[3];
            s[0]  += xv * w0.x; s[1]  += xv * w0.y; s[2]  += xv * w0.z; s[3]  += xv * w0.w;
            s[4]  += xv * w1.x; s[5]  += xv * w1.y; s[6]  += xv * w1.z; s[7]  += xv * w1.w;
            s[8]  += xv * w2.x; s[9]  += xv * w2.y; s[10] += xv * w2.z; s[11] += xv * w2.w;
            s[12] += xv * w3.x; s[13] += xv * w3.y; s[14] += xv * w3.z; s[15] += xv * w3.w;
        }
    }

    // stage sraw^T
#pragma unroll
    for (int k = 0; k < 16; ++k) Sg[k * SROW + lane] = (h16)s[k];

    // softmax
    float m = s[0];
#pragma unroll
    for (int k = 1; k < 16; ++k) m = fmaxf(m, s[k]);
    float sum = 0.f;
#pragma unroll
    for (int k = 0; k < 16; ++k) { s[k] = __expf(s[k] - m); sum += s[k]; }
    float inv = 1.0f / sum;
#pragma unroll
    for (int k = 0; k < 16; ++k) s[k] *= inv;

    // stage ss^T (f16, for CC MFMA)
    f16x8 h0, h1;
#pragma unroll
    for (int k = 0; k < 8; ++k) { h0[k] = (h16)s[k]; h1[k] = (h16)s[k + 8]; }
#pragma unroll
    for (int k = 0; k < 8; ++k) {
        Cg[k * SROW + lane] = h0[k];
        Cg[(k + 8) * SROW + lane] = h1[k];
    }

    // global ssh write: fp8 e4m3, 16 B/node (one dwordx4)
    {
        unsigned d0, d1, d2, d3;
        d0 = __builtin_amdgcn_cvt_pk_fp8_f32(s[0],  s[1],  0,  false);
        d0 = __builtin_amdgcn_cvt_pk_fp8_f32(s[2],  s[3],  d0, true);
        d1 = __builtin_amdgcn_cvt_pk_fp8_f32(s[4],  s[5],  0,  false);
        d1 = __builtin_amdgcn_cvt_pk_fp8_f32(s[6],  s[7],  d1, true);
        d2 = __builtin_amdgcn_cvt_pk_fp8_f32(s[8],  s[9],  0,  false);
        d2 = __builtin_amdgcn_cvt_pk_fp8_f32(s[10], s[11], d2, true);
        d3 = __builtin_amdgcn_cvt_pk_fp8_f32(s[12], s[13], 0,  false);
        d3 = __builtin_amdgcn_cvt_pk_fp8_f32(s[14], s[15], d3, true);
        uint4 pk; pk.x = d0; pk.y = d1; pk.z = d2; pk.w = d3;
        ssh8[i] = pk;
    }

    // MFMA phase (wave-private LDS, no barrier needed)
    int q4 = lane >> 4, mm = lane & 15;
    f32x4 accO[4] = {{0.f,0.f,0.f,0.f},{0.f,0.f,0.f,0.f},{0.f,0.f,0.f,0.f},{0.f,0.f,0.f,0.f}};
    f32x4 accC = {0.f, 0.f, 0.f, 0.f};
#pragma unroll
    for (int h = 0; h < 2; ++h) {
        f16x8 aO = *(const f16x8*)&Sg[mm * SROW + h * 32 + q4 * 8];
        f16x8 aC = *(const f16x8*)&Cg[mm * SROW + h * 32 + q4 * 8];
        accC = __builtin_amdgcn_mfma_f32_16x16x32_f16(aC, aC, accC, 0, 0, 0);
#pragma unroll
        for (int ft = 0; ft < 4; ++ft) {
            f16x8 bO = *(const f16x8*)&Xg[(ft * 16 + mm) * SROW + h * 32 + q4 * 8];
            accO[ft] = __builtin_amdgcn_mfma_f32_16x16x32_f16(aO, bO, accO[ft], 0, 0, 0);
        }
    }
    __syncthreads();

    // block reduce (reuse staging LDS)
    float* redO = (float*)&stage[0][0];     // 4 x 1024
    float* redC = redO + 4096;              // 4 x 256
#pragma unroll
    for (int ft = 0; ft < 4; ++ft)
#pragma unroll
        for (int rg = 0; rg < 4; ++rg)
            redO[wid * 1024 + (q4 * 4 + rg) * 64 + ft * 16 + mm] = accO[ft][rg];
#pragma unroll
    for (int rg = 0; rg < 4; ++rg)
        redC[wid * 256 + (q4 * 4 + rg) * 16 + mm] = accC[rg];
    __syncthreads();

    int g = blockIdx.x >> 5;    // 32 blocks per graph
#pragma unroll
    for (int it = 0; it < 4; ++it) {
        int idx = t + it * 256;
        float v = redO[idx] + redO[1024 + idx] + redO[2048 + idx] + redO[3072 + idx];
        atomicAdd(outx + g * 1024 + idx, v);
    }
    {
        float v = redC[t] + redC[256 + t] + redC[512 + t] + redC[768 + t];
        atomicAdd(CCb + g * 256 + t, v);
    }
}

// ---------------------------------------------------------------------------
// K2 v6: fp8 gathers -- the divergent lane-ADDRESS count is the binding
// resource (5 structural variants all pinned at ~60us == 256 addr/tile x
// ~2cy). fp8 rows are 16 B: ONE lane fetches a full edge-row with ONE
// address -> 2 gather instrs/tile (128 lane-addresses) instead of 4 (256).
// Decode fp8->f16 in registers (cvt_pk_f32_fp8 + cvt_pkrtz), stage the
// BYTE-IDENTICAL f16 LDS image as round 2, so the verified tr-read + MFMA
// path is unchanged. Keep the 2-ahead global prefetch pipeline.
// ---------------------------------------------------------------------------
__global__ __launch_bounds__(256) void k_edge(
    const int* __restrict__ erow, const int* __restrict__ ecol, const float* __restrict__ ew,
    const uint4* __restrict__ ssh8, float* __restrict__ oadj,
    int edges_per_block, int edges_per_graph, int nmask)
{
    __shared__ float CCl[256];
    __shared__ __align__(16) h16 stageE[4][2048];   // per wave: A[64][16] + B[64][16] = 4 KB
    int t = threadIdx.x;
    CCl[t] = 0.f;
    __syncthreads();

    int bid = blockIdx.x;
    int xcd = bid & 7;
    int slot = bid >> 3;
    int graph = xcd + 8 * (slot & 1);
    int chunk = slot >> 1;

    int wid = t >> 6, lane = t & 63;
    int q4 = lane >> 4, mm = lane & 15;
    h16* Ag = stageE[wid];

    int epw = edges_per_block >> 2;           // 512 edges per wave
    int nt  = epw >> 6;                       // 8 tiles of 64 edges
    size_t base = (size_t)graph * edges_per_graph
                + (size_t)chunk * edges_per_block
                + (size_t)wid * epw
                + lane;                       // 1 lane per edge

    f32x4 acc = {0.f, 0.f, 0.f, 0.f};

    // LDS image (identical to round 2): A rows [64 edges][16 f16] at 32 B
    // stride starting at 0; B rows at +2048 B.
    f16x8* Aw = reinterpret_cast<f16x8*>(Ag);
    using lds_h16 = __attribute__((address_space(3))) h16;
    unsigned trA = (unsigned)(uintptr_t)(lds_h16*)Ag + (unsigned)(q4 * 256 + mm * 2);

    // decode one fp8 dword -> 4 f16 (2 packed dwords), scaled by w
    auto dec_dw = [](unsigned d, float w, unsigned& o0, unsigned& o1) {
        fx2 p = __builtin_amdgcn_cvt_pk_f32_fp8((int)d, false);
        fx2 q = __builtin_amdgcn_cvt_pk_f32_fp8((int)d, true);
        o0 = h2u(__builtin_amdgcn_cvt_pkrtz(p.x * w, p.y * w));
        o1 = h2u(__builtin_amdgcn_cvt_pkrtz(q.x * w, q.y * w));
    };

    // per-tile: decode A (w-scaled) + B, stage, tr-read, 2 MFMAs
    auto compute_tile = [&](uint4 va, uint4 vb, float wv) {
        union { unsigned u[4]; f16x8 v; } alo, ahi, blo, bhi;
        dec_dw(va.x, wv, alo.u[0], alo.u[1]);
        dec_dw(va.y, wv, alo.u[2], alo.u[3]);
        dec_dw(va.z, wv, ahi.u[0], ahi.u[1]);
        dec_dw(va.w, wv, ahi.u[2], ahi.u[3]);
        dec_dw(vb.x, 1.0f, blo.u[0], blo.u[1]);
        dec_dw(vb.y, 1.0f, blo.u[2], blo.u[3]);
        dec_dw(vb.z, 1.0f, bhi.u[0], bhi.u[1]);
        dec_dw(vb.w, 1.0f, bhi.u[2], bhi.u[3]);

        // lane e writes its full 32 B row (A) and 32 B row (B)
        Aw[lane * 2]           = alo.v;
        Aw[lane * 2 + 1]       = ahi.v;
        Aw[128 + lane * 2]     = blo.v;
        Aw[128 + lane * 2 + 1] = bhi.v;

        f16x4 xa0, xa1, xa2, xa3, xb0, xb1, xb2, xb3;
        asm volatile(
            "ds_read_b64_tr_b16 %0, %8\n\t"
            "ds_read_b64_tr_b16 %1, %8 offset:128\n\t"
            "ds_read_b64_tr_b16 %2, %8 offset:2048\n\t"
            "ds_read_b64_tr_b16 %3, %8 offset:2176\n\t"
            "ds_read_b64_tr_b16 %4, %8 offset:1024\n\t"
            "ds_read_b64_tr_b16 %5, %8 offset:1152\n\t"
            "ds_read_b64_tr_b16 %6, %8 offset:3072\n\t"
            "ds_read_b64_tr_b16 %7, %8 offset:3200\n\t"
            "s_waitcnt lgkmcnt(0)"
            : "=&v"(xa0), "=&v"(xa1), "=&v"(xb0), "=&v"(xb1),
              "=&v"(xa2), "=&v"(xa3), "=&v"(xb2), "=&v"(xb3)
            : "v"(trA)
            : "memory");
        __builtin_amdgcn_sched_barrier(0);

        f16x8 afL = __builtin_shufflevector(xa0, xa1, 0, 1, 2, 3, 4, 5, 6, 7);
        f16x8 bfL = __builtin_shufflevector(xb0, xb1, 0, 1, 2, 3, 4, 5, 6, 7);
        f16x8 afH = __builtin_shufflevector(xa2, xa3, 0, 1, 2, 3, 4, 5, 6, 7);
        f16x8 bfH = __builtin_shufflevector(xb2, xb3, 0, 1, 2, 3, 4, 5, 6, 7);
        acc = __builtin_amdgcn_mfma_f32_16x16x32_f16(afL, bfL, acc, 0, 0, 0);
        acc = __builtin_amdgcn_mfma_f32_16x16x32_f16(afH, bfH, acc, 0, 0, 0);
    };

    // ---- pipeline prologue: idx(0), gathers(0), idx(1) ----
    int rC, cC; float wC;
    rC = erow[base]; cC = ecol[base]; wC = ew[base];
    uint4 ca = ssh8[(size_t)(rC & nmask)];
    uint4 cb = ssh8[(size_t)(cC & nmask)];
    int rN = 0, cN = 0; float wN = 0.f;
    {
        size_t e = base + 64;
        rN = erow[e]; cN = ecol[e]; wN = ew[e];
    }

    // ---- steady state: gathers(t+1) + idx(t+2) issued before compute(t) ----
    for (int tt = 0; tt < nt - 1; ++tt) {
        uint4 na = ssh8[(size_t)(rN & nmask)];
        uint4 nb = ssh8[(size_t)(cN & nmask)];
        int t2 = (tt + 2 < nt) ? (tt + 2) : 0;
        size_t e2 = base + (size_t)t2 * 64;
        int r2 = erow[e2], c2 = ecol[e2];
        float w2 = ew[e2];

        compute_tile(ca, cb, wC);

        ca = na; cb = nb; wC = wN;
        rN = r2; cN = c2; wN = w2;
    }
    // ---- epilogue: last tile ----
    compute_tile(ca, cb, wC);

    // reduce: acc[rg] is oadj[row = q4*4+rg][col = mm] contribution
#pragma unroll
    for (int rg = 0; rg < 4; ++rg)
        atomicAdd(&CCl[(q4 * 4 + rg) * 16 + mm], acc[rg]);
    __syncthreads();
    atomicAdd(oadj + graph * 256 + t, CCl[t]);
}

// ---------------------------------------------------------------------------
// K3: unchanged from baseline.
// ---------------------------------------------------------------------------
__global__ __launch_bounds__(256) void k_final(
    const float* __restrict__ outx, const float* __restrict__ oadj,
    const float* __restrict__ CCb, float* __restrict__ out, int npg)
{
    int t = threadIdx.x;
    int gid = blockIdx.x * 256 + t;
    {
        float v = outx[gid];
        float r = (v > 0.f) ? (1.0507009873554805f * v)
                            : (1.0507009873554805f * 1.6732632423543772f * (__expf(v) - 1.0f));
        out[gid] = r;
    }

    if (blockIdx.x != 0) return;

    int b = t >> 4, k = t & 15;
    const float* oar = oadj + b * 256 + k * 16;
    const float* ccr = CCb + b * 256 + k * 16;

    float rowsum_off = 0.f, trace_c = 0.f, rowsum_all = 0.f, fro2 = 0.f, colsum = 0.f;
    float csv = 0.f;
#pragma unroll
    for (int l = 0; l < 16; ++l) {
        float v = oar[l];
        rowsum_all += v;
        if (l == k) trace_c = v; else rowsum_off += v;
        float c = ccr[l];
        fro2 += c * c;
        csv += c;                              // cluster_size[k] = sum_l CC[k][l]
        colsum += oadj[b * 256 + l * 16 + k];
    }
    float dd = sqrtf(rowsum_off) + 1e-12f;
    __shared__ float ddl[B_GR * K_CL];
    ddl[t] = dd;

    float ds2 = colsum * colsum, cs2 = csv * csv;
    float tr = trace_c, m2 = rowsum_all;
#pragma unroll
    for (int msk = 8; msk >= 1; msk >>= 1) {
        tr   += __shfl_xor(tr,   msk, 16);
        ds2  += __shfl_xor(ds2,  msk, 16);
        cs2  += __shfl_xor(cs2,  msk, 16);
        fro2 += __shfl_xor(fro2, msk, 16);
        m2   += __shfl_xor(m2,   msk, 16);
    }
    float invfro = 1.0f / sqrtf(fro2);
    float osum = 0.f;
#pragma unroll
    for (int l = 0; l < 16; ++l) {
        float v = ccr[l] * invfro - ((l == k) ? 0.25f : 0.f);
        osum += v * v;
    }
#pragma unroll
    for (int msk = 8; msk >= 1; msk >>= 1) osum += __shfl_xor(osum, msk, 16);

    __shared__ float sp_s[B_GR], cl_s[B_GR], or_s[B_GR];
    if (k == 0) {
        sp_s[b] = tr / m2 - ds2 / (m2 * m2);
        cl_s[b] = sqrtf(cs2) / (float)npg * 4.0f - 1.0f;
        or_s[b] = sqrtf(osum);
    }
    __syncthreads();
    if (t == 0) {
        float a = 0.f, c = 0.f, o = 0.f;
        for (int i = 0; i < B_GR; ++i) { a += sp_s[i]; c += cl_s[i]; o += or_s[i]; }
        out[20480] = -a / 16.f;
        out[20481] = c / 16.f;
        out[20482] = o / 16.f;
    }

#pragma unroll
    for (int l = 0; l < 16; ++l) {
        float v = (l == k) ? 0.f : oar[l] / (dd * ddl[b * 16 + l]);
        out[16384 + b * 256 + k * 16 + l] = v;
    }
}

// ---------------------------------------------------------------------------
extern "C" void kernel_launch(void* const* d_in, const int* in_sizes, int n_in,
                              void* d_out, int out_size, void* d_ws, size_t ws_size,
                              hipStream_t stream)
{
    const float* x    = (const float*)d_in[0];
    const float* W    = (const float*)d_in[1];
    const float* bvec = (const float*)d_in[2];
    const float* ew   = (const float*)d_in[3];
    const int* erow   = (const int*)d_in[4];
    const int* ecol   = (const int*)d_in[5];

    int Ntot = in_sizes[0] / F_DIM;           // 131072
    size_t E = (size_t)in_sizes[3];           // 4194304
    int npg  = Ntot / B_GR;                   // 8192
    int edges_per_graph = (int)(E / B_GR);    // 262144
    int nmask = Ntot - 1;

    const int ADJ_BLOCKS = 2048;              // 128 per graph, 8 per CU
    int edges_per_block = (int)(E / ADJ_BLOCKS);          // 2048

    char* ws = (char*)d_ws;
    size_t o = 0;
    uint4* ssh8  = (uint4*)(ws + o); o += (size_t)Ntot * 16;   // fp8 rows, 16 B/node
    size_t zoff = o;
    float* outx  = (float*)(ws + o); o += (size_t)B_GR * 1024 * 4;
    float* oadj  = (float*)(ws + o); o += (size_t)B_GR * 256 * 4;
    float* CCb   = (float*)(ws + o); o += (size_t)B_GR * 256 * 4;

    (void)hipMemsetAsync(ws + zoff, 0, o - zoff, stream);

    k_fused<<<Ntot / 256, 256, 0, stream>>>(x, W, bvec, ssh8, outx, CCb);
    k_edge<<<ADJ_BLOCKS, 256, 0, stream>>>(erow, ecol, ew, ssh8, oadj,
                                           edges_per_block, edges_per_graph, nmask);
    k_final<<<64, 256, 0, stream>>>(outx, oadj, CCb, (float*)d_out, npg);
}